// Round 1
// baseline (1803.782 us; speedup 1.0000x reference)
//
#include <hip/hip_runtime.h>
#include <hip/hip_bf16.h>
#include <cstdint>

// Problem constants
#define B_   64
#define T_   2048
#define CIN  44
#define D_   512
#define DCC  640
#define REDD 160
#define BT   131072        // B_*T_
#define EPSV 1e-5f

typedef __attribute__((ext_vector_type(8))) short short8;
typedef __attribute__((ext_vector_type(4))) float f32x4;

#define MFMA16(a,b,c) __builtin_amdgcn_mfma_f32_16x16x32_bf16(a,b,c,0,0,0)

__device__ __forceinline__ float bf2f(unsigned short u) {
    union { unsigned int i; float f; } v; v.i = ((unsigned int)u) << 16; return v.f;
}
__device__ __forceinline__ unsigned short f2bf(float f) {
    union { float f; unsigned int i; } v; v.f = f;
    unsigned int r = v.i + 0x7FFFu + ((v.i >> 16) & 1u);   // RNE
    return (unsigned short)(r >> 16);
}

// ---------------------------------------------------------------- prep: weights -> bf16 FRAGMENT-PACKED
// Packed layout: for chunk c (64 cols), K-slab kb (32 k), tile t (16 cols):
//   packed[ ((c*(K/32) + kb)*4 + t)*512 + lane*8 + j ]  = W^T[n][k]
// with lane = quad*16+lid, n = c*64 + t*16 + lid, k = kb*32 + quad*8 + j.
// A wave's B-fragment load is then ONE contiguous 1KB coalesced dwordx4.
__global__ void kprep(const float* __restrict__ hw1, const float* __restrict__ lw1, const float* __restrict__ ew1,
                      const float* __restrict__ hb1, const float* __restrict__ lb1, const float* __restrict__ eb1,
                      const float* __restrict__ hw2, const float* __restrict__ lw2, const float* __restrict__ ew2,
                      const float* __restrict__ hb2, const float* __restrict__ lb2, const float* __restrict__ eb2,
                      const float* __restrict__ gw,  const float* __restrict__ pw,  const float* __restrict__ ow,
                      unsigned short* __restrict__ w1T, float* __restrict__ b1,
                      unsigned short* __restrict__ w2T, float* __restrict__ b2,
                      unsigned short* __restrict__ gwT, unsigned short* __restrict__ pwT,
                      unsigned short* __restrict__ owT)
{
    int tid = blockIdx.x * blockDim.x + threadIdx.x;
    int nth = gridDim.x * blockDim.x;
    // gwT/pwT: N=640, K=640 -> chunk size 20*2048 = 40960
    for (int i = tid; i < 640 * 640; i += nth) {
        int c  = i / 40960, r = i - c * 40960;
        int kb = r / 2048;  int r2 = r - kb * 2048;
        int t  = r2 >> 9;   int l8 = r2 & 511;
        int lane = l8 >> 3, j = l8 & 7;
        int lid = lane & 15, quad = lane >> 4;
        int n = c * 64 + t * 16 + lid;
        int k = kb * 32 + quad * 8 + j;
        gwT[i] = f2bf(gw[(size_t)k * 640 + n]);
        pwT[i] = f2bf(pw[(size_t)k * 640 + n]);
    }
    // owT: N=512, K=640 (ow stride 512!)
    for (int i = tid; i < 512 * 640; i += nth) {
        int c  = i / 40960, r = i - c * 40960;
        int kb = r / 2048;  int r2 = r - kb * 2048;
        int t  = r2 >> 9;   int l8 = r2 & 511;
        int lane = l8 >> 3, j = l8 & 7;
        int lid = lane & 15, quad = lane >> 4;
        int n = c * 64 + t * 16 + lid;
        int k = kb * 32 + quad * 8 + j;
        owT[i] = f2bf(ow[(size_t)k * 512 + n]);
    }
    // w2T: N=640, K=256 local -> chunk size 8*2048 = 16384; block-diag groups
    for (int i = tid; i < 640 * 256; i += nth) {
        int c  = i / 16384, r = i - c * 16384;
        int kb = r / 2048;  int r2 = r - kb * 2048;
        int t  = r2 >> 9;   int l8 = r2 & 511;
        int lane = l8 >> 3, j = l8 & 7;
        int lid = lane & 15, quad = lane >> 4;
        int n = c * 64 + t * 16 + lid;
        int k = kb * 32 + quad * 8 + j;   // local k within group
        float v;
        if (n < 256)      v = hw2[k * 256 + n];
        else if (n < 512) v = lw2[k * 256 + (n - 256)];
        else              v = (k < 128) ? ew2[k * 128 + (n - 512)] : 0.0f;
        w2T[i] = f2bf(v);
    }
    // w1T: stage-1 weights, K padded to 32 per group (true K = 14/22/8).
    // Layout: w1T[ct*512 + lane*8 + j], n = ct*16+lid, k_local = quad*8+j.
    for (int i = tid; i < 640 * 32; i += nth) {
        int ct = i >> 9;  int l8 = i & 511;
        int lane = l8 >> 3, j = l8 & 7;
        int lid = lane & 15, quad = lane >> 4;
        int n = ct * 16 + lid;
        int k = quad * 8 + j;
        float v = 0.0f;
        if (n < 256)      { if (k < 14) v = hw1[k * 256 + n]; }
        else if (n < 512) { if (k < 22) v = lw1[k * 256 + (n - 256)]; }
        else              { if (k < 8)  v = ew1[k * 128 + (n - 512)]; }
        w1T[i] = f2bf(v);
    }
    for (int i = tid; i < 640; i += nth) {
        b1[i] = (i < 256) ? hb1[i] : ((i < 512) ? lb1[i - 256] : eb1[i - 512]);
        b2[i] = (i < 256) ? hb2[i] : ((i < 512) ? lb2[i - 256] : eb2[i - 512]);
    }
}

// ---------------------------------------------------------------- fused stage 1+2:
// u = silu(x @ blockdiag(W1) + b1)   (in LDS only, never touches HBM)
// z = u @ blockdiag(W2) + b2 ; y_sum
// Wave-retile: each wave owns ALL 32 rows x 160 cols (tiles wave+4i) ->
// every B fragment feeds 2 MFMAs, no wave-pair duplication.
__global__ __launch_bounds__(256) void k_z(const float* __restrict__ x,
                                           const unsigned short* __restrict__ w1T,
                                           const float* __restrict__ b1,
                                           const unsigned short* __restrict__ w2T,
                                           const float* __restrict__ b2,
                                           unsigned short* __restrict__ z,
                                           float* __restrict__ y_sum)
{
    __shared__ __align__(16) unsigned short sx[32 * 96];    // x padded to 3 K-slabs of 32
    __shared__ __align__(16) unsigned short su[32 * 648];
    int m0 = blockIdx.x * 32;
    int bidx = m0 >> 11;
    // stage x -> bf16, zero-padded slabs: [0:14]->slab0, [14:36]->slab1, [36:44]->slab2
    const float* xsrc = x + (size_t)m0 * CIN;
    for (int i = threadIdx.x; i < 32 * 96; i += 256) {
        int r = i / 96, c = i - r * 96;
        int slab = c >> 5, kc = c & 31;
        float v = 0.0f;
        if (slab == 0)      { if (kc < 14) v = xsrc[r * CIN + kc]; }
        else if (slab == 1) { if (kc < 22) v = xsrc[r * CIN + 14 + kc]; }
        else                { if (kc < 8)  v = xsrc[r * CIN + 36 + kc]; }
        sx[i] = f2bf(v);
    }
    __syncthreads();
    int wave = threadIdx.x >> 6, lane = threadIdx.x & 63, lid = lane & 15, quad = lane >> 4;
    const f32x4 z4 = {0.f, 0.f, 0.f, 0.f};
    // ---- stage 1: one K=32 MFMA per 16-col tile, silu -> su
    #pragma unroll
    for (int i = 0; i < 10; i++) {
        int ct = wave + 4 * i;
        int slab = i >> 2;                       // tiles 0-15 grp h, 16-31 grp l, 32-39 grp e
        short8 bfr = *(const short8*)(w1T + (size_t)ct * 512 + lane * 8);
        short8 a0 = *(const short8*)&sx[lid * 96 + slab * 32 + quad * 8];
        short8 a1 = *(const short8*)&sx[(16 + lid) * 96 + slab * 32 + quad * 8];
        f32x4 u0 = MFMA16(a0, bfr, z4);
        f32x4 u1 = MFMA16(a1, bfr, z4);
        int col = ct * 16 + lid;
        float bias = b1[col];
        #pragma unroll
        for (int r = 0; r < 4; r++) {
            float v0 = u0[r] + bias;
            su[(quad * 4 + r) * 648 + col] = f2bf(v0 / (1.0f + __expf(-v0)));
            float v1 = u1[r] + bias;
            su[(16 + quad * 4 + r) * 648 + col] = f2bf(v1 / (1.0f + __expf(-v1)));
        }
    }
    __syncthreads();
    // ---- stage 2: block-diag GEMM. grp0/grp1 K=256, grp2 (tiles 32-39) K=128.
    f32x4 acc[10][2];
    #pragma unroll
    for (int i = 0; i < 10; i++) { acc[i][0] = z4; acc[i][1] = z4; }
    for (int kk = 0; kk < 256; kk += 32) {
        int kb = kk >> 5;
        short8 a00 = *(const short8*)&su[lid * 648 + kk + quad * 8];
        short8 a01 = *(const short8*)&su[(16 + lid) * 648 + kk + quad * 8];
        short8 a10 = *(const short8*)&su[lid * 648 + 256 + kk + quad * 8];
        short8 a11 = *(const short8*)&su[(16 + lid) * 648 + 256 + kk + quad * 8];
        #pragma unroll
        for (int i = 0; i < 8; i++) {
            int ct = wave + 4 * i;
            const short8 a0 = (i < 4) ? a00 : a10;
            const short8 a1 = (i < 4) ? a01 : a11;
            const unsigned short* bb = w2T + (size_t)((((ct >> 2) * 8 + kb) * 4) + (ct & 3)) * 512 + lane * 8;
            short8 bf = *(const short8*)bb;
            acc[i][0] = MFMA16(a0, bf, acc[i][0]);
            acc[i][1] = MFMA16(a1, bf, acc[i][1]);
        }
        if (kk < 128) {
            short8 a20 = *(const short8*)&su[lid * 648 + 512 + kk + quad * 8];
            short8 a21 = *(const short8*)&su[(16 + lid) * 648 + 512 + kk + quad * 8];
            #pragma unroll
            for (int i = 8; i < 10; i++) {
                int ct = wave + 4 * i;
                const unsigned short* bb = w2T + (size_t)((((ct >> 2) * 8 + kb) * 4) + (ct & 3)) * 512 + lane * 8;
                short8 bf = *(const short8*)bb;
                acc[i][0] = MFMA16(a20, bf, acc[i][0]);
                acc[i][1] = MFMA16(a21, bf, acc[i][1]);
            }
        }
    }
    #pragma unroll
    for (int i = 0; i < 10; i++) {
        int ct = wave + 4 * i;
        int col = ct * 16 + lid;
        float bias = b2[col];
        float colsum = 0.0f;
        #pragma unroll
        for (int rs = 0; rs < 2; rs++) {
            #pragma unroll
            for (int r = 0; r < 4; r++) {
                float zv = acc[i][rs][r] + bias;
                z[(size_t)(m0 + rs * 16 + quad * 4 + r) * 640 + col] = f2bf(zv);
                colsum += zv;
            }
        }
        colsum += __shfl_xor(colsum, 16);
        colsum += __shfl_xor(colsum, 32);
        if (quad == 0) atomicAdd(&y_sum[bidx * 640 + col], colsum);
    }
}

// ---------------------------------------------------------------- SE MLP per batch
__global__ void k_se(const float* __restrict__ y_sum, const float* __restrict__ se_w1,
                     const float* __restrict__ se_w2, float* __restrict__ se)
{
    __shared__ float ya[640];
    __shared__ float rr[160];
    int b = blockIdx.x;
    for (int i = threadIdx.x; i < 640; i += 256) ya[i] = y_sum[b * 640 + i] * (1.0f / 2048.0f);
    __syncthreads();
    for (int o = threadIdx.x; o < 160; o += 256) {
        float a = 0.f;
        for (int k = 0; k < 640; k++) a += ya[k] * se_w1[k * 160 + o];
        rr[o] = fmaxf(a, 0.f);
    }
    __syncthreads();
    for (int c = threadIdx.x; c < 640; c += 256) {
        float a = 0.f;
        for (int o = 0; o < 160; o++) a += rr[o] * se_w2[o * 640 + c];
        se[b * 640 + c] = 1.0f / (1.0f + __expf(-a));
    }
}

// ---------------------------------------------------------------- GLU: g/p GEMMs + h + LN stats
// Wave-retile: wave owns 32 rows x 160 cols (tiles wave+4i).
__global__ __launch_bounds__(256) void k_glu(const unsigned short* __restrict__ z,
                                             const float* __restrict__ se,
                                             const unsigned short* __restrict__ gwT,
                                             const unsigned short* __restrict__ pwT,
                                             const float* __restrict__ gb, const float* __restrict__ pb,
                                             unsigned short* __restrict__ h, float* __restrict__ hstats)
{
    __shared__ __align__(16) unsigned short sz[32 * 648];
    int m0 = blockIdx.x * 32;
    int bidx = m0 >> 11;
    const unsigned short* zsrc = z + (size_t)m0 * 640;
    const float* seb = se + bidx * 640;
    for (int i = threadIdx.x; i < 2560; i += 256) {        // stage z_se = bf16(z * se)
        int e = i * 8, r = e / 640, c = e - r * 640;
        short8 v = *(const short8*)(zsrc + e);
        unsigned short o8[8];
        #pragma unroll
        for (int j = 0; j < 8; j++) {
            float f = bf2f(((const unsigned short*)&v)[j]) * seb[c + j];
            o8[j] = f2bf(f);
        }
        *(short8*)&sz[r * 648 + c] = *(short8*)o8;
    }
    __syncthreads();
    int wave = threadIdx.x >> 6, lane = threadIdx.x & 63, lid = lane & 15, quad = lane >> 4;
    const f32x4 z4 = {0.f, 0.f, 0.f, 0.f};
    f32x4 ag[10][2], ap[10][2];
    #pragma unroll
    for (int i = 0; i < 10; i++) { ag[i][0] = z4; ag[i][1] = z4; ap[i][0] = z4; ap[i][1] = z4; }
    for (int kk = 0; kk < 640; kk += 32) {
        int kb = kk >> 5;
        short8 a0 = *(const short8*)&sz[lid * 648 + kk + quad * 8];
        short8 a1 = *(const short8*)&sz[(16 + lid) * 648 + kk + quad * 8];
        #pragma unroll
        for (int i = 0; i < 10; i++) {
            int ct = wave + 4 * i;
            size_t bbase = (size_t)((((ct >> 2) * 20 + kb) * 4) + (ct & 3)) * 512 + lane * 8;
            short8 vg = *(const short8*)(gwT + bbase);
            ag[i][0] = MFMA16(a0, vg, ag[i][0]);
            ag[i][1] = MFMA16(a1, vg, ag[i][1]);
            short8 vp = *(const short8*)(pwT + bbase);
            ap[i][0] = MFMA16(a0, vp, ap[i][0]);
            ap[i][1] = MFMA16(a1, vp, ap[i][1]);
        }
    }
    float hs[2][4] = {{0.f,0.f,0.f,0.f},{0.f,0.f,0.f,0.f}};
    float hq[2][4] = {{0.f,0.f,0.f,0.f},{0.f,0.f,0.f,0.f}};
    #pragma unroll
    for (int i = 0; i < 10; i++) {
        int ct = wave + 4 * i;
        int col = ct * 16 + lid;
        float gbv = gb[col], pbv = pb[col];
        #pragma unroll
        for (int rs = 0; rs < 2; rs++) {
            #pragma unroll
            for (int r = 0; r < 4; r++) {
                int row = rs * 16 + quad * 4 + r;
                float gl = ag[i][rs][r] + gbv;
                float pl = ap[i][rs][r] + pbv;
                float sg = 1.0f / (1.0f + __expf(-gl));
                float zv = bf2f(sz[row * 648 + col]);
                float hv = sg * pl + (1.0f - sg) * zv;
                h[(size_t)(m0 + row) * 640 + col] = f2bf(hv);
                hs[rs][r] += hv; hq[rs][r] += hv * hv;
            }
        }
    }
    #pragma unroll
    for (int s = 1; s < 16; s <<= 1) {
        #pragma unroll
        for (int rs = 0; rs < 2; rs++)
            #pragma unroll
            for (int r = 0; r < 4; r++) {
                hs[rs][r] += __shfl_xor(hs[rs][r], s);
                hq[rs][r] += __shfl_xor(hq[rs][r], s);
            }
    }
    if (lid == 0) {
        #pragma unroll
        for (int rs = 0; rs < 2; rs++)
            #pragma unroll
            for (int r = 0; r < 4; r++) {
                int row = m0 + rs * 16 + quad * 4 + r;
                atomicAdd(&hstats[row * 2 + 0], hs[rs][r]);
                atomicAdd(&hstats[row * 2 + 1], hq[rs][r]);
            }
    }
}

// ---------------------------------------------------------------- LN + out-proj GEMM + GN stats
// Wave-retile: wave owns 32 rows x 128 cols (tiles wave+4i, i<8).
__global__ __launch_bounds__(256) void k_out(const unsigned short* __restrict__ h,
                                             const float* __restrict__ hstats,
                                             const float* __restrict__ ln_w, const float* __restrict__ ln_b,
                                             const unsigned short* __restrict__ owT,
                                             const float* __restrict__ ob,
                                             float* __restrict__ outp, float* __restrict__ gnstats)
{
    __shared__ __align__(16) unsigned short sh[32 * 648];
    __shared__ float sA[32], sB[32];
    int m0 = blockIdx.x * 32;
    int bidx = m0 >> 11;
    if (threadIdx.x < 32) {
        float s1 = hstats[(m0 + threadIdx.x) * 2 + 0];
        float s2 = hstats[(m0 + threadIdx.x) * 2 + 1];
        float mu = s1 * (1.0f / 640.0f);
        float var = s2 * (1.0f / 640.0f) - mu * mu;
        float rs = rsqrtf(var + EPSV);
        sA[threadIdx.x] = rs;
        sB[threadIdx.x] = -mu * rs;
    }
    __syncthreads();
    const unsigned short* hsrc = h + (size_t)m0 * 640;
    for (int i = threadIdx.x; i < 2560; i += 256) {        // stage h_ln = bf16(LN(h))
        int e = i * 8, r = e / 640, c = e - r * 640;
        short8 v = *(const short8*)(hsrc + e);
        float a = sA[r], bb = sB[r];
        unsigned short o8[8];
        #pragma unroll
        for (int j = 0; j < 8; j++) {
            float f = bf2f(((const unsigned short*)&v)[j]);
            f = f * a + bb;
            f = f * ln_w[c + j] + ln_b[c + j];
            o8[j] = f2bf(f);
        }
        *(short8*)&sh[r * 648 + c] = *(short8*)o8;
    }
    __syncthreads();
    int wave = threadIdx.x >> 6, lane = threadIdx.x & 63, lid = lane & 15, quad = lane >> 4;
    const f32x4 z4 = {0.f, 0.f, 0.f, 0.f};
    f32x4 acc[8][2];
    #pragma unroll
    for (int i = 0; i < 8; i++) { acc[i][0] = z4; acc[i][1] = z4; }
    for (int kk = 0; kk < 640; kk += 32) {
        int kb = kk >> 5;
        short8 a0 = *(const short8*)&sh[lid * 648 + kk + quad * 8];
        short8 a1 = *(const short8*)&sh[(16 + lid) * 648 + kk + quad * 8];
        #pragma unroll
        for (int i = 0; i < 8; i++) {
            // ct = wave + 4*i -> chunk = i (== GN group), tile-in-chunk = wave
            const unsigned short* bb = owT + (size_t)(((i * 20 + kb) * 4) + wave) * 512 + lane * 8;
            short8 bo = *(const short8*)bb;
            acc[i][0] = MFMA16(a0, bo, acc[i][0]);
            acc[i][1] = MFMA16(a1, bo, acc[i][1]);
        }
    }
    #pragma unroll
    for (int i = 0; i < 8; i++) {
        int ct = wave + 4 * i;
        int col = ct * 16 + lid;
        float obv = ob[col];
        float gs = 0.f, gq = 0.f;
        #pragma unroll
        for (int rs = 0; rs < 2; rs++) {
            #pragma unroll
            for (int r = 0; r < 4; r++) {
                int row = rs * 16 + quad * 4 + r;
                float v = acc[i][rs][r] + obv;
                outp[(size_t)(m0 + row) * 512 + col] = v;
                gs += v; gq += v * v;
            }
        }
        #pragma unroll
        for (int s = 1; s < 64; s <<= 1) { gs += __shfl_xor(gs, s); gq += __shfl_xor(gq, s); }
        if (lane == 0) {
            atomicAdd(&gnstats[(bidx * 8 + i) * 2 + 0], gs);
            atomicAdd(&gnstats[(bidx * 8 + i) * 2 + 1], gq);
        }
    }
}

// ---------------------------------------------------------------- GroupNorm finalize (in-place on d_out)
__global__ void k_gn(float* __restrict__ outp, const float* __restrict__ gnstats,
                     const float* __restrict__ gn_w, const float* __restrict__ gn_b)
{
    int idx = blockIdx.x * 256 + threadIdx.x;
    size_t e = (size_t)idx * 4;
    int c = (int)(e & 511);
    size_t row = e >> 9;
    int b = (int)(row >> 11);
    int grp = c >> 6;
    float s1 = gnstats[(b * 8 + grp) * 2 + 0];
    float s2 = gnstats[(b * 8 + grp) * 2 + 1];
    const float inv = 1.0f / 131072.0f;
    float mu = s1 * inv;
    float var = s2 * inv - mu * mu;
    float rs = rsqrtf(var + EPSV);
    float4 v = *(const float4*)(outp + e);
    float4 w = *(const float4*)(gn_w + c);
    float4 bb = *(const float4*)(gn_b + c);
    float4 o;
    o.x = (v.x - mu) * rs * w.x + bb.x;
    o.y = (v.y - mu) * rs * w.y + bb.y;
    o.z = (v.z - mu) * rs * w.z + bb.z;
    o.w = (v.w - mu) * rs * w.w + bb.w;
    *(float4*)(outp + e) = o;
}

// ----------------------------------------------------------------
extern "C" void kernel_launch(void* const* d_in, const int* in_sizes, int n_in,
                              void* d_out, int out_size, void* d_ws, size_t ws_size,
                              hipStream_t stream)
{
    const float* x     = (const float*)d_in[0];
    const float* hw1   = (const float*)d_in[1];
    const float* hb1   = (const float*)d_in[2];
    const float* hw2   = (const float*)d_in[3];
    const float* hb2   = (const float*)d_in[4];
    const float* lw1   = (const float*)d_in[5];
    const float* lb1   = (const float*)d_in[6];
    const float* lw2   = (const float*)d_in[7];
    const float* lb2   = (const float*)d_in[8];
    const float* ew1   = (const float*)d_in[9];
    const float* eb1   = (const float*)d_in[10];
    const float* ew2   = (const float*)d_in[11];
    const float* eb2   = (const float*)d_in[12];
    const float* se_w1 = (const float*)d_in[13];
    const float* se_w2 = (const float*)d_in[14];
    const float* gw    = (const float*)d_in[15];
    const float* gb    = (const float*)d_in[16];
    const float* pw    = (const float*)d_in[17];
    const float* pb    = (const float*)d_in[18];
    const float* ln_w  = (const float*)d_in[19];
    const float* ln_b  = (const float*)d_in[20];
    const float* ow    = (const float*)d_in[21];
    const float* ob    = (const float*)d_in[22];
    const float* gn_w  = (const float*)d_in[23];
    const float* gn_b  = (const float*)d_in[24];

    char* ws = (char*)d_ws;
    size_t off = 0;
    unsigned short* w2T  = (unsigned short*)(ws + off); off += (size_t)640 * 256 * 2;
    float*          b2   = (float*)(ws + off);          off += 640 * 4;
    unsigned short* gwT  = (unsigned short*)(ws + off); off += (size_t)640 * 640 * 2;
    unsigned short* pwT  = (unsigned short*)(ws + off); off += (size_t)640 * 640 * 2;
    unsigned short* owT  = (unsigned short*)(ws + off); off += (size_t)512 * 640 * 2;
    unsigned short* w1T  = (unsigned short*)(ws + off); off += (size_t)640 * 32 * 2;
    float*          b1   = (float*)(ws + off);          off += 640 * 4;
    float*          ysum = (float*)(ws + off);          off += (size_t)64 * 640 * 4;
    float*          sebuf= (float*)(ws + off);          off += (size_t)64 * 640 * 4;
    float*          hstat= (float*)(ws + off);          off += (size_t)BT * 2 * 4;
    float*          gnst = (float*)(ws + off);          off += (size_t)64 * 8 * 2 * 4;
    unsigned short* hbuf = (unsigned short*)(ws + off); off += (size_t)BT * 640 * 2;

    unsigned short* zbuf = (unsigned short*)d_out;
    float*          outp = (float*)d_out;

    hipMemsetAsync(ysum, 0, (size_t)64 * 640 * 4, stream);
    hipMemsetAsync(hstat, 0, (size_t)BT * 2 * 4, stream);
    hipMemsetAsync(gnst, 0, (size_t)64 * 8 * 2 * 4, stream);

    kprep<<<512, 256, 0, stream>>>(hw1, lw1, ew1, hb1, lb1, eb1,
                                   hw2, lw2, ew2, hb2, lb2, eb2,
                                   gw, pw, ow, w1T, b1, w2T, b2, gwT, pwT, owT);
    k_z<<<BT / 32, 256, 0, stream>>>(x, w1T, b1, w2T, b2, zbuf, ysum);
    k_se<<<64, 256, 0, stream>>>(ysum, se_w1, se_w2, sebuf);
    k_glu<<<BT / 32, 256, 0, stream>>>(zbuf, sebuf, gwT, pwT, gb, pb, hbuf, hstat);
    k_out<<<BT / 32, 256, 0, stream>>>(hbuf, hstat, ln_w, ln_b, owT, ob, outp, gnst);
    k_gn<<<(BT * 512) / (256 * 4), 256, 0, stream>>>(outp, gnst, gn_w, gn_b);
}

// Round 2
// 1310.875 us; speedup vs baseline: 1.3760x; 1.3760x over previous
//
#include <hip/hip_runtime.h>
#include <hip/hip_bf16.h>
#include <cstdint>

// Problem constants
#define B_   64
#define T_   2048
#define CIN  44
#define D_   512
#define DCC  640
#define REDD 160
#define BT   131072        // B_*T_
#define EPSV 1e-5f

typedef __attribute__((ext_vector_type(8))) short short8;
typedef __attribute__((ext_vector_type(4))) float f32x4;

#define MFMA16(a,b,c) __builtin_amdgcn_mfma_f32_16x16x32_bf16(a,b,c,0,0,0)

__device__ __forceinline__ float bf2f(unsigned short u) {
    union { unsigned int i; float f; } v; v.i = ((unsigned int)u) << 16; return v.f;
}
__device__ __forceinline__ unsigned short f2bf(float f) {
    union { float f; unsigned int i; } v; v.f = f;
    unsigned int r = v.i + 0x7FFFu + ((v.i >> 16) & 1u);   // RNE
    return (unsigned short)(r >> 16);
}

// ---------------------------------------------------------------- prep: weights -> bf16 FRAGMENT-PACKED
// Packed layout: for chunk c (64 cols), K-slab kb (32 k), tile t (16 cols):
//   packed[ ((c*(K/32) + kb)*4 + t)*512 + lane*8 + j ]  = W^T[n][k]
// with lane = quad*16+lid, n = c*64 + t*16 + lid, k = kb*32 + quad*8 + j.
// A wave's B-fragment load is then ONE contiguous 1KB coalesced dwordx4.
__global__ void kprep(const float* __restrict__ hw1, const float* __restrict__ lw1, const float* __restrict__ ew1,
                      const float* __restrict__ hb1, const float* __restrict__ lb1, const float* __restrict__ eb1,
                      const float* __restrict__ hw2, const float* __restrict__ lw2, const float* __restrict__ ew2,
                      const float* __restrict__ hb2, const float* __restrict__ lb2, const float* __restrict__ eb2,
                      const float* __restrict__ gw,  const float* __restrict__ pw,  const float* __restrict__ ow,
                      unsigned short* __restrict__ w1T, float* __restrict__ b1,
                      unsigned short* __restrict__ w2T, float* __restrict__ b2,
                      unsigned short* __restrict__ gwT, unsigned short* __restrict__ pwT,
                      unsigned short* __restrict__ owT)
{
    int tid = blockIdx.x * blockDim.x + threadIdx.x;
    int nth = gridDim.x * blockDim.x;
    // gwT/pwT: N=640, K=640 -> chunk size 20*2048 = 40960
    for (int i = tid; i < 640 * 640; i += nth) {
        int c  = i / 40960, r = i - c * 40960;
        int kb = r / 2048;  int r2 = r - kb * 2048;
        int t  = r2 >> 9;   int l8 = r2 & 511;
        int lane = l8 >> 3, j = l8 & 7;
        int lid = lane & 15, quad = lane >> 4;
        int n = c * 64 + t * 16 + lid;
        int k = kb * 32 + quad * 8 + j;
        gwT[i] = f2bf(gw[(size_t)k * 640 + n]);
        pwT[i] = f2bf(pw[(size_t)k * 640 + n]);
    }
    // owT: N=512, K=640 (ow stride 512!)
    for (int i = tid; i < 512 * 640; i += nth) {
        int c  = i / 40960, r = i - c * 40960;
        int kb = r / 2048;  int r2 = r - kb * 2048;
        int t  = r2 >> 9;   int l8 = r2 & 511;
        int lane = l8 >> 3, j = l8 & 7;
        int lid = lane & 15, quad = lane >> 4;
        int n = c * 64 + t * 16 + lid;
        int k = kb * 32 + quad * 8 + j;
        owT[i] = f2bf(ow[(size_t)k * 512 + n]);
    }
    // w2T: N=640, K=256 local -> chunk size 8*2048 = 16384; block-diag groups
    for (int i = tid; i < 640 * 256; i += nth) {
        int c  = i / 16384, r = i - c * 16384;
        int kb = r / 2048;  int r2 = r - kb * 2048;
        int t  = r2 >> 9;   int l8 = r2 & 511;
        int lane = l8 >> 3, j = l8 & 7;
        int lid = lane & 15, quad = lane >> 4;
        int n = c * 64 + t * 16 + lid;
        int k = kb * 32 + quad * 8 + j;   // local k within group
        float v;
        if (n < 256)      v = hw2[k * 256 + n];
        else if (n < 512) v = lw2[k * 256 + (n - 256)];
        else              v = (k < 128) ? ew2[k * 128 + (n - 512)] : 0.0f;
        w2T[i] = f2bf(v);
    }
    // w1T: stage-1 weights, K padded to 32 per group (true K = 14/22/8).
    for (int i = tid; i < 640 * 32; i += nth) {
        int ct = i >> 9;  int l8 = i & 511;
        int lane = l8 >> 3, j = l8 & 7;
        int lid = lane & 15, quad = lane >> 4;
        int n = ct * 16 + lid;
        int k = quad * 8 + j;
        float v = 0.0f;
        if (n < 256)      { if (k < 14) v = hw1[k * 256 + n]; }
        else if (n < 512) { if (k < 22) v = lw1[k * 256 + (n - 256)]; }
        else              { if (k < 8)  v = ew1[k * 128 + (n - 512)]; }
        w1T[i] = f2bf(v);
    }
    for (int i = tid; i < 640; i += nth) {
        b1[i] = (i < 256) ? hb1[i] : ((i < 512) ? lb1[i - 256] : eb1[i - 512]);
        b2[i] = (i < 256) ? hb2[i] : ((i < 512) ? lb2[i - 256] : eb2[i - 512]);
    }
}

// ---------------------------------------------------------------- fused stage 1+2 (8 waves, M=32)
// u = silu(x @ blockdiag(W1) + b1)   (LDS only)
// z = u @ blockdiag(W2) + b2 ; y_sum
// Each wave owns 32 rows x 5 tiles (ct = wave + 8i); B prefetch is full
// k-step double-buffered (ping-pong bA/bB) so loads overlap MFMAs.
#define ZSTEP(KB, CUR, NXT) { \
    const int kk = (KB) * 32; \
    short8 a00 = *(const short8*)&su[lid * 648 + kk + quad * 8]; \
    short8 a01 = *(const short8*)&su[(16 + lid) * 648 + kk + quad * 8]; \
    short8 a10 = *(const short8*)&su[lid * 648 + 256 + kk + quad * 8]; \
    short8 a11 = *(const short8*)&su[(16 + lid) * 648 + 256 + kk + quad * 8]; \
    if ((KB) + 1 < 8) { \
        NXT[0] = *(const short8*)(w2T + off[0] + ((KB) + 1) * 2048); \
        NXT[1] = *(const short8*)(w2T + off[1] + ((KB) + 1) * 2048); \
        NXT[2] = *(const short8*)(w2T + off[2] + ((KB) + 1) * 2048); \
        NXT[3] = *(const short8*)(w2T + off[3] + ((KB) + 1) * 2048); \
        if ((KB) + 1 < 4) NXT[4] = *(const short8*)(w2T + off[4] + ((KB) + 1) * 2048); \
    } \
    acc[0][0] = MFMA16(a00, CUR[0], acc[0][0]); acc[0][1] = MFMA16(a01, CUR[0], acc[0][1]); \
    acc[1][0] = MFMA16(a00, CUR[1], acc[1][0]); acc[1][1] = MFMA16(a01, CUR[1], acc[1][1]); \
    acc[2][0] = MFMA16(a10, CUR[2], acc[2][0]); acc[2][1] = MFMA16(a11, CUR[2], acc[2][1]); \
    acc[3][0] = MFMA16(a10, CUR[3], acc[3][0]); acc[3][1] = MFMA16(a11, CUR[3], acc[3][1]); \
    if ((KB) < 4) { \
        short8 a20 = *(const short8*)&su[lid * 648 + 512 + kk + quad * 8]; \
        short8 a21 = *(const short8*)&su[(16 + lid) * 648 + 512 + kk + quad * 8]; \
        acc[4][0] = MFMA16(a20, CUR[4], acc[4][0]); acc[4][1] = MFMA16(a21, CUR[4], acc[4][1]); \
    } }

__global__ __launch_bounds__(512) void k_z(const float* __restrict__ x,
                                           const unsigned short* __restrict__ w1T,
                                           const float* __restrict__ b1,
                                           const unsigned short* __restrict__ w2T,
                                           const float* __restrict__ b2,
                                           unsigned short* __restrict__ z,
                                           float* __restrict__ y_sum)
{
    __shared__ __align__(16) unsigned short sx[32 * 96];
    __shared__ __align__(16) unsigned short su[32 * 648];
    int m0 = blockIdx.x * 32;
    int bidx = m0 >> 11;
    const float* xsrc = x + (size_t)m0 * CIN;
    for (int i = threadIdx.x; i < 32 * 96; i += 512) {
        int r = i / 96, c = i - r * 96;
        int slab = c >> 5, kc = c & 31;
        float v = 0.0f;
        if (slab == 0)      { if (kc < 14) v = xsrc[r * CIN + kc]; }
        else if (slab == 1) { if (kc < 22) v = xsrc[r * CIN + 14 + kc]; }
        else                { if (kc < 8)  v = xsrc[r * CIN + 36 + kc]; }
        sx[i] = f2bf(v);
    }
    __syncthreads();
    int wave = threadIdx.x >> 6, lane = threadIdx.x & 63, lid = lane & 15, quad = lane >> 4;
    const f32x4 z4 = {0.f, 0.f, 0.f, 0.f};
    // ---- stage 1
    #pragma unroll
    for (int i = 0; i < 5; i++) {
        int ct = wave + 8 * i;
        int slab = ct >> 4;
        short8 bfr = *(const short8*)(w1T + (size_t)ct * 512 + lane * 8);
        short8 a0 = *(const short8*)&sx[lid * 96 + slab * 32 + quad * 8];
        short8 a1 = *(const short8*)&sx[(16 + lid) * 96 + slab * 32 + quad * 8];
        f32x4 u0 = MFMA16(a0, bfr, z4);
        f32x4 u1 = MFMA16(a1, bfr, z4);
        int col = ct * 16 + lid;
        float bias = b1[col];
        #pragma unroll
        for (int r = 0; r < 4; r++) {
            float v0 = u0[r] + bias;
            su[(quad * 4 + r) * 648 + col] = f2bf(v0 / (1.0f + __expf(-v0)));
            float v1 = u1[r] + bias;
            su[(16 + quad * 4 + r) * 648 + col] = f2bf(v1 / (1.0f + __expf(-v1)));
        }
    }
    __syncthreads();
    // ---- stage 2
    int off[5];
    #pragma unroll
    for (int i = 0; i < 5; i++) {
        int ct = wave + 8 * i;
        off[i] = ((ct >> 2) * 32 + (ct & 3)) * 512 + lane * 8;
    }
    f32x4 acc[5][2];
    #pragma unroll
    for (int i = 0; i < 5; i++) { acc[i][0] = z4; acc[i][1] = z4; }
    short8 bA[5], bB[5];
    #pragma unroll
    for (int i = 0; i < 5; i++) bA[i] = *(const short8*)(w2T + off[i]);
    ZSTEP(0, bA, bB) ZSTEP(1, bB, bA) ZSTEP(2, bA, bB) ZSTEP(3, bB, bA)
    ZSTEP(4, bA, bB) ZSTEP(5, bB, bA) ZSTEP(6, bA, bB) ZSTEP(7, bB, bA)
    #pragma unroll
    for (int i = 0; i < 5; i++) {
        int ct = wave + 8 * i;
        int col = ct * 16 + lid;
        float bias = b2[col];
        float colsum = 0.0f;
        #pragma unroll
        for (int rs = 0; rs < 2; rs++) {
            #pragma unroll
            for (int r = 0; r < 4; r++) {
                float zv = acc[i][rs][r] + bias;
                z[(size_t)(m0 + rs * 16 + quad * 4 + r) * 640 + col] = f2bf(zv);
                colsum += zv;
            }
        }
        colsum += __shfl_xor(colsum, 16);
        colsum += __shfl_xor(colsum, 32);
        if (quad == 0) atomicAdd(&y_sum[bidx * 640 + col], colsum);
    }
}

// ---------------------------------------------------------------- SE MLP per batch
__global__ void k_se(const float* __restrict__ y_sum, const float* __restrict__ se_w1,
                     const float* __restrict__ se_w2, float* __restrict__ se)
{
    __shared__ float ya[640];
    __shared__ float rr[160];
    int b = blockIdx.x;
    for (int i = threadIdx.x; i < 640; i += 256) ya[i] = y_sum[b * 640 + i] * (1.0f / 2048.0f);
    __syncthreads();
    for (int o = threadIdx.x; o < 160; o += 256) {
        float a = 0.f;
        for (int k = 0; k < 640; k++) a += ya[k] * se_w1[k * 160 + o];
        rr[o] = fmaxf(a, 0.f);
    }
    __syncthreads();
    for (int c = threadIdx.x; c < 640; c += 256) {
        float a = 0.f;
        for (int o = 0; o < 160; o++) a += rr[o] * se_w2[o * 640 + c];
        se[b * 640 + c] = 1.0f / (1.0f + __expf(-a));
    }
}

// ---------------------------------------------------------------- GLU: g/p GEMMs + h + LN stats (8 waves, M=32)
// Half-k-step rotation: issue P(kb) loads -> G-MFMAs(kb) -> issue G(kb+1) -> P-MFMAs(kb).
__global__ __launch_bounds__(512) void k_glu(const unsigned short* __restrict__ z,
                                             const float* __restrict__ se,
                                             const unsigned short* __restrict__ gwT,
                                             const unsigned short* __restrict__ pwT,
                                             const float* __restrict__ gb, const float* __restrict__ pb,
                                             unsigned short* __restrict__ h, float* __restrict__ hstats)
{
    __shared__ __align__(16) unsigned short sz[32 * 648];
    int m0 = blockIdx.x * 32;
    int bidx = m0 >> 11;
    const unsigned short* zsrc = z + (size_t)m0 * 640;
    const float* seb = se + bidx * 640;
    for (int i = threadIdx.x; i < 2560; i += 512) {        // stage z_se = bf16(z * se)
        int e = i * 8, r = e / 640, c = e - r * 640;
        short8 v = *(const short8*)(zsrc + e);
        unsigned short o8[8];
        #pragma unroll
        for (int j = 0; j < 8; j++) {
            float f = bf2f(((const unsigned short*)&v)[j]) * seb[c + j];
            o8[j] = f2bf(f);
        }
        *(short8*)&sz[r * 648 + c] = *(short8*)o8;
    }
    __syncthreads();
    int wave = threadIdx.x >> 6, lane = threadIdx.x & 63, lid = lane & 15, quad = lane >> 4;
    const f32x4 z4 = {0.f, 0.f, 0.f, 0.f};
    int off[5];
    #pragma unroll
    for (int i = 0; i < 5; i++) {
        int ct = wave + 8 * i;
        off[i] = ((ct >> 2) * 80 + (ct & 3)) * 512 + lane * 8;
    }
    f32x4 ag[5][2], ap[5][2];
    #pragma unroll
    for (int i = 0; i < 5; i++) { ag[i][0] = z4; ag[i][1] = z4; ap[i][0] = z4; ap[i][1] = z4; }
    short8 gbuf[5], pbuf[5];
    #pragma unroll
    for (int i = 0; i < 5; i++) gbuf[i] = *(const short8*)(gwT + off[i]);
    for (int kb = 0; kb < 19; kb++) {
        int kk = kb * 32;
        short8 a0 = *(const short8*)&sz[lid * 648 + kk + quad * 8];
        short8 a1 = *(const short8*)&sz[(16 + lid) * 648 + kk + quad * 8];
        #pragma unroll
        for (int i = 0; i < 5; i++) pbuf[i] = *(const short8*)(pwT + off[i] + kk * 64);
        #pragma unroll
        for (int i = 0; i < 5; i++) {
            ag[i][0] = MFMA16(a0, gbuf[i], ag[i][0]);
            ag[i][1] = MFMA16(a1, gbuf[i], ag[i][1]);
        }
        #pragma unroll
        for (int i = 0; i < 5; i++) gbuf[i] = *(const short8*)(gwT + off[i] + kk * 64 + 2048);
        #pragma unroll
        for (int i = 0; i < 5; i++) {
            ap[i][0] = MFMA16(a0, pbuf[i], ap[i][0]);
            ap[i][1] = MFMA16(a1, pbuf[i], ap[i][1]);
        }
    }
    {   // kb = 19 (no prefetch)
        const int kk = 19 * 32;
        short8 a0 = *(const short8*)&sz[lid * 648 + kk + quad * 8];
        short8 a1 = *(const short8*)&sz[(16 + lid) * 648 + kk + quad * 8];
        #pragma unroll
        for (int i = 0; i < 5; i++) pbuf[i] = *(const short8*)(pwT + off[i] + kk * 64);
        #pragma unroll
        for (int i = 0; i < 5; i++) {
            ag[i][0] = MFMA16(a0, gbuf[i], ag[i][0]);
            ag[i][1] = MFMA16(a1, gbuf[i], ag[i][1]);
            ap[i][0] = MFMA16(a0, pbuf[i], ap[i][0]);
            ap[i][1] = MFMA16(a1, pbuf[i], ap[i][1]);
        }
    }
    float hs[2][4] = {{0.f,0.f,0.f,0.f},{0.f,0.f,0.f,0.f}};
    float hq[2][4] = {{0.f,0.f,0.f,0.f},{0.f,0.f,0.f,0.f}};
    #pragma unroll
    for (int i = 0; i < 5; i++) {
        int ct = wave + 8 * i;
        int col = ct * 16 + lid;
        float gbv = gb[col], pbv = pb[col];
        #pragma unroll
        for (int rs = 0; rs < 2; rs++) {
            #pragma unroll
            for (int r = 0; r < 4; r++) {
                int row = rs * 16 + quad * 4 + r;
                float gl = ag[i][rs][r] + gbv;
                float pl = ap[i][rs][r] + pbv;
                float sg = 1.0f / (1.0f + __expf(-gl));
                float zv = bf2f(sz[row * 648 + col]);
                float hv = sg * pl + (1.0f - sg) * zv;
                h[(size_t)(m0 + row) * 640 + col] = f2bf(hv);
                hs[rs][r] += hv; hq[rs][r] += hv * hv;
            }
        }
    }
    #pragma unroll
    for (int s = 1; s < 16; s <<= 1) {
        #pragma unroll
        for (int rs = 0; rs < 2; rs++)
            #pragma unroll
            for (int r = 0; r < 4; r++) {
                hs[rs][r] += __shfl_xor(hs[rs][r], s);
                hq[rs][r] += __shfl_xor(hq[rs][r], s);
            }
    }
    if (lid == 0) {
        #pragma unroll
        for (int rs = 0; rs < 2; rs++)
            #pragma unroll
            for (int r = 0; r < 4; r++) {
                int row = m0 + rs * 16 + quad * 4 + r;
                atomicAdd(&hstats[row * 2 + 0], hs[rs][r]);
                atomicAdd(&hstats[row * 2 + 1], hq[rs][r]);
            }
    }
}

// ---------------------------------------------------------------- LN + out-proj GEMM + GN stats (8 waves, M=64)
// Each wave owns 64 rows x 4 tiles (ct = wave + 8i); full k-step dbuf.
#define OSTEP(KB, CUR, NXT) { \
    const int kk = (KB) * 32; \
    short8 a0 = *(const short8*)&sh[(0 * 16 + lid) * 648 + kk + quad * 8]; \
    short8 a1 = *(const short8*)&sh[(1 * 16 + lid) * 648 + kk + quad * 8]; \
    short8 a2 = *(const short8*)&sh[(2 * 16 + lid) * 648 + kk + quad * 8]; \
    short8 a3 = *(const short8*)&sh[(3 * 16 + lid) * 648 + kk + quad * 8]; \
    if ((KB) < 19) { \
        NXT[0] = *(const short8*)(owT + off[0] + ((KB) + 1) * 2048); \
        NXT[1] = *(const short8*)(owT + off[1] + ((KB) + 1) * 2048); \
        NXT[2] = *(const short8*)(owT + off[2] + ((KB) + 1) * 2048); \
        NXT[3] = *(const short8*)(owT + off[3] + ((KB) + 1) * 2048); \
    } \
    acc[0][0] = MFMA16(a0, CUR[0], acc[0][0]); acc[0][1] = MFMA16(a1, CUR[0], acc[0][1]); \
    acc[0][2] = MFMA16(a2, CUR[0], acc[0][2]); acc[0][3] = MFMA16(a3, CUR[0], acc[0][3]); \
    acc[1][0] = MFMA16(a0, CUR[1], acc[1][0]); acc[1][1] = MFMA16(a1, CUR[1], acc[1][1]); \
    acc[1][2] = MFMA16(a2, CUR[1], acc[1][2]); acc[1][3] = MFMA16(a3, CUR[1], acc[1][3]); \
    acc[2][0] = MFMA16(a0, CUR[2], acc[2][0]); acc[2][1] = MFMA16(a1, CUR[2], acc[2][1]); \
    acc[2][2] = MFMA16(a2, CUR[2], acc[2][2]); acc[2][3] = MFMA16(a3, CUR[2], acc[2][3]); \
    acc[3][0] = MFMA16(a0, CUR[3], acc[3][0]); acc[3][1] = MFMA16(a1, CUR[3], acc[3][1]); \
    acc[3][2] = MFMA16(a2, CUR[3], acc[3][2]); acc[3][3] = MFMA16(a3, CUR[3], acc[3][3]); }

__global__ __launch_bounds__(512) void k_out(const unsigned short* __restrict__ h,
                                             const float* __restrict__ hstats,
                                             const float* __restrict__ ln_w, const float* __restrict__ ln_b,
                                             const unsigned short* __restrict__ owT,
                                             const float* __restrict__ ob,
                                             float* __restrict__ outp, float* __restrict__ gnstats)
{
    __shared__ __align__(16) unsigned short sh[64 * 648];
    __shared__ float sA[64], sB[64];
    int m0 = blockIdx.x * 64;
    int bidx = m0 >> 11;
    if (threadIdx.x < 64) {
        float s1 = hstats[(m0 + threadIdx.x) * 2 + 0];
        float s2 = hstats[(m0 + threadIdx.x) * 2 + 1];
        float mu = s1 * (1.0f / 640.0f);
        float var = s2 * (1.0f / 640.0f) - mu * mu;
        float rs = rsqrtf(var + EPSV);
        sA[threadIdx.x] = rs;
        sB[threadIdx.x] = -mu * rs;
    }
    __syncthreads();
    const unsigned short* hsrc = h + (size_t)m0 * 640;
    for (int i = threadIdx.x; i < 5120; i += 512) {        // stage h_ln = bf16(LN(h))
        int e = i * 8, r = e / 640, c = e - r * 640;
        short8 v = *(const short8*)(hsrc + e);
        float a = sA[r], bb = sB[r];
        unsigned short o8[8];
        #pragma unroll
        for (int j = 0; j < 8; j++) {
            float f = bf2f(((const unsigned short*)&v)[j]);
            f = f * a + bb;
            f = f * ln_w[c + j] + ln_b[c + j];
            o8[j] = f2bf(f);
        }
        *(short8*)&sh[r * 648 + c] = *(short8*)o8;
    }
    __syncthreads();
    int wave = threadIdx.x >> 6, lane = threadIdx.x & 63, lid = lane & 15, quad = lane >> 4;
    const f32x4 z4 = {0.f, 0.f, 0.f, 0.f};
    int off[4];
    #pragma unroll
    for (int i = 0; i < 4; i++) {
        int ct = wave + 8 * i;
        off[i] = ((ct >> 2) * 80 + (ct & 3)) * 512 + lane * 8;
    }
    f32x4 acc[4][4];
    #pragma unroll
    for (int i = 0; i < 4; i++) {
        acc[i][0] = z4; acc[i][1] = z4; acc[i][2] = z4; acc[i][3] = z4;
    }
    short8 bA[4], bB[4];
    #pragma unroll
    for (int i = 0; i < 4; i++) bA[i] = *(const short8*)(owT + off[i]);
    OSTEP(0, bA, bB)  OSTEP(1, bB, bA)  OSTEP(2, bA, bB)  OSTEP(3, bB, bA)
    OSTEP(4, bA, bB)  OSTEP(5, bB, bA)  OSTEP(6, bA, bB)  OSTEP(7, bB, bA)
    OSTEP(8, bA, bB)  OSTEP(9, bB, bA)  OSTEP(10, bA, bB) OSTEP(11, bB, bA)
    OSTEP(12, bA, bB) OSTEP(13, bB, bA) OSTEP(14, bA, bB) OSTEP(15, bB, bA)
    OSTEP(16, bA, bB) OSTEP(17, bB, bA) OSTEP(18, bA, bB) OSTEP(19, bB, bA)
    #pragma unroll
    for (int i = 0; i < 4; i++) {
        int ct = wave + 8 * i;
        int col = ct * 16 + lid;
        float obv = ob[col];
        float gs = 0.f, gq = 0.f;
        #pragma unroll
        for (int rf = 0; rf < 4; rf++) {
            #pragma unroll
            for (int r = 0; r < 4; r++) {
                int row = rf * 16 + quad * 4 + r;
                float v = acc[i][rf][r] + obv;
                outp[(size_t)(m0 + row) * 512 + col] = v;
                gs += v; gq += v * v;
            }
        }
        #pragma unroll
        for (int s = 1; s < 64; s <<= 1) { gs += __shfl_xor(gs, s); gq += __shfl_xor(gq, s); }
        if (lane == 0) {
            int grp = ct >> 2;
            atomicAdd(&gnstats[(bidx * 8 + grp) * 2 + 0], gs);
            atomicAdd(&gnstats[(bidx * 8 + grp) * 2 + 1], gq);
        }
    }
}

// ---------------------------------------------------------------- GroupNorm finalize (in-place on d_out)
__global__ void k_gn(float* __restrict__ outp, const float* __restrict__ gnstats,
                     const float* __restrict__ gn_w, const float* __restrict__ gn_b)
{
    int idx = blockIdx.x * 256 + threadIdx.x;
    size_t e = (size_t)idx * 4;
    int c = (int)(e & 511);
    size_t row = e >> 9;
    int b = (int)(row >> 11);
    int grp = c >> 6;
    float s1 = gnstats[(b * 8 + grp) * 2 + 0];
    float s2 = gnstats[(b * 8 + grp) * 2 + 1];
    const float inv = 1.0f / 131072.0f;
    float mu = s1 * inv;
    float var = s2 * inv - mu * mu;
    float rs = rsqrtf(var + EPSV);
    float4 v = *(const float4*)(outp + e);
    float4 w = *(const float4*)(gn_w + c);
    float4 bb = *(const float4*)(gn_b + c);
    float4 o;
    o.x = (v.x - mu) * rs * w.x + bb.x;
    o.y = (v.y - mu) * rs * w.y + bb.y;
    o.z = (v.z - mu) * rs * w.z + bb.z;
    o.w = (v.w - mu) * rs * w.w + bb.w;
    *(float4*)(outp + e) = o;
}

// ----------------------------------------------------------------
extern "C" void kernel_launch(void* const* d_in, const int* in_sizes, int n_in,
                              void* d_out, int out_size, void* d_ws, size_t ws_size,
                              hipStream_t stream)
{
    const float* x     = (const float*)d_in[0];
    const float* hw1   = (const float*)d_in[1];
    const float* hb1   = (const float*)d_in[2];
    const float* hw2   = (const float*)d_in[3];
    const float* hb2   = (const float*)d_in[4];
    const float* lw1   = (const float*)d_in[5];
    const float* lb1   = (const float*)d_in[6];
    const float* lw2   = (const float*)d_in[7];
    const float* lb2   = (const float*)d_in[8];
    const float* ew1   = (const float*)d_in[9];
    const float* eb1   = (const float*)d_in[10];
    const float* ew2   = (const float*)d_in[11];
    const float* eb2   = (const float*)d_in[12];
    const float* se_w1 = (const float*)d_in[13];
    const float* se_w2 = (const float*)d_in[14];
    const float* gw    = (const float*)d_in[15];
    const float* gb    = (const float*)d_in[16];
    const float* pw    = (const float*)d_in[17];
    const float* pb    = (const float*)d_in[18];
    const float* ln_w  = (const float*)d_in[19];
    const float* ln_b  = (const float*)d_in[20];
    const float* ow    = (const float*)d_in[21];
    const float* ob    = (const float*)d_in[22];
    const float* gn_w  = (const float*)d_in[23];
    const float* gn_b  = (const float*)d_in[24];

    char* ws = (char*)d_ws;
    size_t off = 0;
    unsigned short* w2T  = (unsigned short*)(ws + off); off += (size_t)640 * 256 * 2;
    float*          b2   = (float*)(ws + off);          off += 640 * 4;
    unsigned short* gwT  = (unsigned short*)(ws + off); off += (size_t)640 * 640 * 2;
    unsigned short* pwT  = (unsigned short*)(ws + off); off += (size_t)640 * 640 * 2;
    unsigned short* owT  = (unsigned short*)(ws + off); off += (size_t)512 * 640 * 2;
    unsigned short* w1T  = (unsigned short*)(ws + off); off += (size_t)640 * 32 * 2;
    float*          b1   = (float*)(ws + off);          off += 640 * 4;
    float*          ysum = (float*)(ws + off);          off += (size_t)64 * 640 * 4;
    float*          sebuf= (float*)(ws + off);          off += (size_t)64 * 640 * 4;
    float*          hstat= (float*)(ws + off);          off += (size_t)BT * 2 * 4;
    float*          gnst = (float*)(ws + off);          off += (size_t)64 * 8 * 2 * 4;
    unsigned short* hbuf = (unsigned short*)(ws + off); off += (size_t)BT * 640 * 2;

    unsigned short* zbuf = (unsigned short*)d_out;
    float*          outp = (float*)d_out;

    hipMemsetAsync(ysum, 0, (size_t)64 * 640 * 4, stream);
    hipMemsetAsync(hstat, 0, (size_t)BT * 2 * 4, stream);
    hipMemsetAsync(gnst, 0, (size_t)64 * 8 * 2 * 4, stream);

    kprep<<<512, 256, 0, stream>>>(hw1, lw1, ew1, hb1, lb1, eb1,
                                   hw2, lw2, ew2, hb2, lb2, eb2,
                                   gw, pw, ow, w1T, b1, w2T, b2, gwT, pwT, owT);
    k_z<<<BT / 32, 512, 0, stream>>>(x, w1T, b1, w2T, b2, zbuf, ysum);
    k_se<<<64, 256, 0, stream>>>(ysum, se_w1, se_w2, sebuf);
    k_glu<<<BT / 32, 512, 0, stream>>>(zbuf, sebuf, gwT, pwT, gb, pb, hbuf, hstat);
    k_out<<<BT / 64, 512, 0, stream>>>(hbuf, hstat, ln_w, ln_b, owT, ob, outp, gnst);
    k_gn<<<(BT * 512) / (256 * 4), 256, 0, stream>>>(outp, gnst, gn_w, gn_b);
}

// Round 3
// 1266.486 us; speedup vs baseline: 1.4242x; 1.0350x over previous
//
#include <hip/hip_runtime.h>
#include <hip/hip_bf16.h>
#include <cstdint>

// Problem constants
#define B_   64
#define T_   2048
#define CIN  44
#define D_   512
#define DCC  640
#define REDD 160
#define BT   131072        // B_*T_
#define EPSV 1e-5f

typedef __attribute__((ext_vector_type(8))) short short8;
typedef __attribute__((ext_vector_type(4))) float f32x4;

#define MFMA16(a,b,c) __builtin_amdgcn_mfma_f32_16x16x32_bf16(a,b,c,0,0,0)

__device__ __forceinline__ float bf2f(unsigned short u) {
    union { unsigned int i; float f; } v; v.i = ((unsigned int)u) << 16; return v.f;
}
__device__ __forceinline__ unsigned short f2bf(float f) {
    union { float f; unsigned int i; } v; v.f = f;
    unsigned int r = v.i + 0x7FFFu + ((v.i >> 16) & 1u);   // RNE
    return (unsigned short)(r >> 16);
}

// ---------------------------------------------------------------- prep: weights -> bf16 FRAGMENT-PACKED
// Packed layout: for chunk c (64 cols), K-slab kb (32 k), tile t (16 cols):
//   packed[ ((c*(K/32) + kb)*4 + t)*512 + lane*8 + j ]  = W^T[n][k]
// with lane = quad*16+lid, n = c*64 + t*16 + lid, k = kb*32 + quad*8 + j.
// A wave's B-fragment load is then ONE contiguous 1KB coalesced dwordx4.
__global__ void kprep(const float* __restrict__ hw1, const float* __restrict__ lw1, const float* __restrict__ ew1,
                      const float* __restrict__ hb1, const float* __restrict__ lb1, const float* __restrict__ eb1,
                      const float* __restrict__ hw2, const float* __restrict__ lw2, const float* __restrict__ ew2,
                      const float* __restrict__ hb2, const float* __restrict__ lb2, const float* __restrict__ eb2,
                      const float* __restrict__ gw,  const float* __restrict__ pw,  const float* __restrict__ ow,
                      unsigned short* __restrict__ w1T, float* __restrict__ b1,
                      unsigned short* __restrict__ w2T, float* __restrict__ b2,
                      unsigned short* __restrict__ gwT, unsigned short* __restrict__ pwT,
                      unsigned short* __restrict__ owT)
{
    int tid = blockIdx.x * blockDim.x + threadIdx.x;
    int nth = gridDim.x * blockDim.x;
    // gwT/pwT: N=640, K=640 -> chunk size 20*2048 = 40960
    for (int i = tid; i < 640 * 640; i += nth) {
        int c  = i / 40960, r = i - c * 40960;
        int kb = r / 2048;  int r2 = r - kb * 2048;
        int t  = r2 >> 9;   int l8 = r2 & 511;
        int lane = l8 >> 3, j = l8 & 7;
        int lid = lane & 15, quad = lane >> 4;
        int n = c * 64 + t * 16 + lid;
        int k = kb * 32 + quad * 8 + j;
        gwT[i] = f2bf(gw[(size_t)k * 640 + n]);
        pwT[i] = f2bf(pw[(size_t)k * 640 + n]);
    }
    // owT: N=512, K=640 (ow stride 512!)
    for (int i = tid; i < 512 * 640; i += nth) {
        int c  = i / 40960, r = i - c * 40960;
        int kb = r / 2048;  int r2 = r - kb * 2048;
        int t  = r2 >> 9;   int l8 = r2 & 511;
        int lane = l8 >> 3, j = l8 & 7;
        int lid = lane & 15, quad = lane >> 4;
        int n = c * 64 + t * 16 + lid;
        int k = kb * 32 + quad * 8 + j;
        owT[i] = f2bf(ow[(size_t)k * 512 + n]);
    }
    // w2T: N=640, K=256 local -> chunk size 8*2048 = 16384; block-diag groups
    for (int i = tid; i < 640 * 256; i += nth) {
        int c  = i / 16384, r = i - c * 16384;
        int kb = r / 2048;  int r2 = r - kb * 2048;
        int t  = r2 >> 9;   int l8 = r2 & 511;
        int lane = l8 >> 3, j = l8 & 7;
        int lid = lane & 15, quad = lane >> 4;
        int n = c * 64 + t * 16 + lid;
        int k = kb * 32 + quad * 8 + j;   // local k within group
        float v;
        if (n < 256)      v = hw2[k * 256 + n];
        else if (n < 512) v = lw2[k * 256 + (n - 256)];
        else              v = (k < 128) ? ew2[k * 128 + (n - 512)] : 0.0f;
        w2T[i] = f2bf(v);
    }
    // w1T: stage-1 weights, K padded to 32 per group (true K = 14/22/8).
    for (int i = tid; i < 640 * 32; i += nth) {
        int ct = i >> 9;  int l8 = i & 511;
        int lane = l8 >> 3, j = l8 & 7;
        int lid = lane & 15, quad = lane >> 4;
        int n = ct * 16 + lid;
        int k = quad * 8 + j;
        float v = 0.0f;
        if (n < 256)      { if (k < 14) v = hw1[k * 256 + n]; }
        else if (n < 512) { if (k < 22) v = lw1[k * 256 + (n - 256)]; }
        else              { if (k < 8)  v = ew1[k * 128 + (n - 512)]; }
        w1T[i] = f2bf(v);
    }
    for (int i = tid; i < 640; i += nth) {
        b1[i] = (i < 256) ? hb1[i] : ((i < 512) ? lb1[i - 256] : eb1[i - 512]);
        b2[i] = (i < 256) ? hb2[i] : ((i < 512) ? lb2[i - 256] : eb2[i - 512]);
    }
}

// ---------------------------------------------------------------- fused stage 1+2 (8 waves, M=64)
// u = silu(x @ blockdiag(W1) + b1)   (LDS only)
// z = u @ blockdiag(W2) + b2 ; y_sum
// Each wave owns 64 rows x 5 tiles (ct = wave + 8i); B is full k-step
// ping-pong double-buffered; each B fragment feeds 4 MFMAs.
#define ZSTEP(KB, CUR, NXT) { \
    const int kk = (KB) * 32; \
    short8 ah0 = *(const short8*)&su[(0*16 + lid) * 648 + kk + quad * 8]; \
    short8 ah1 = *(const short8*)&su[(1*16 + lid) * 648 + kk + quad * 8]; \
    short8 ah2 = *(const short8*)&su[(2*16 + lid) * 648 + kk + quad * 8]; \
    short8 ah3 = *(const short8*)&su[(3*16 + lid) * 648 + kk + quad * 8]; \
    short8 al0 = *(const short8*)&su[(0*16 + lid) * 648 + 256 + kk + quad * 8]; \
    short8 al1 = *(const short8*)&su[(1*16 + lid) * 648 + 256 + kk + quad * 8]; \
    short8 al2 = *(const short8*)&su[(2*16 + lid) * 648 + 256 + kk + quad * 8]; \
    short8 al3 = *(const short8*)&su[(3*16 + lid) * 648 + 256 + kk + quad * 8]; \
    if ((KB) + 1 < 8) { \
        NXT[0] = *(const short8*)(w2T + off[0] + ((KB) + 1) * 2048); \
        NXT[1] = *(const short8*)(w2T + off[1] + ((KB) + 1) * 2048); \
        NXT[2] = *(const short8*)(w2T + off[2] + ((KB) + 1) * 2048); \
        NXT[3] = *(const short8*)(w2T + off[3] + ((KB) + 1) * 2048); \
        if ((KB) + 1 < 4) NXT[4] = *(const short8*)(w2T + off[4] + ((KB) + 1) * 2048); \
    } \
    acc[0][0] = MFMA16(ah0, CUR[0], acc[0][0]); acc[0][1] = MFMA16(ah1, CUR[0], acc[0][1]); \
    acc[0][2] = MFMA16(ah2, CUR[0], acc[0][2]); acc[0][3] = MFMA16(ah3, CUR[0], acc[0][3]); \
    acc[1][0] = MFMA16(ah0, CUR[1], acc[1][0]); acc[1][1] = MFMA16(ah1, CUR[1], acc[1][1]); \
    acc[1][2] = MFMA16(ah2, CUR[1], acc[1][2]); acc[1][3] = MFMA16(ah3, CUR[1], acc[1][3]); \
    acc[2][0] = MFMA16(al0, CUR[2], acc[2][0]); acc[2][1] = MFMA16(al1, CUR[2], acc[2][1]); \
    acc[2][2] = MFMA16(al2, CUR[2], acc[2][2]); acc[2][3] = MFMA16(al3, CUR[2], acc[2][3]); \
    acc[3][0] = MFMA16(al0, CUR[3], acc[3][0]); acc[3][1] = MFMA16(al1, CUR[3], acc[3][1]); \
    acc[3][2] = MFMA16(al2, CUR[3], acc[3][2]); acc[3][3] = MFMA16(al3, CUR[3], acc[3][3]); \
    if ((KB) < 4) { \
        short8 ae0 = *(const short8*)&su[(0*16 + lid) * 648 + 512 + kk + quad * 8]; \
        short8 ae1 = *(const short8*)&su[(1*16 + lid) * 648 + 512 + kk + quad * 8]; \
        short8 ae2 = *(const short8*)&su[(2*16 + lid) * 648 + 512 + kk + quad * 8]; \
        short8 ae3 = *(const short8*)&su[(3*16 + lid) * 648 + 512 + kk + quad * 8]; \
        acc[4][0] = MFMA16(ae0, CUR[4], acc[4][0]); acc[4][1] = MFMA16(ae1, CUR[4], acc[4][1]); \
        acc[4][2] = MFMA16(ae2, CUR[4], acc[4][2]); acc[4][3] = MFMA16(ae3, CUR[4], acc[4][3]); \
    } }

__global__ __launch_bounds__(512) void k_z(const float* __restrict__ x,
                                           const unsigned short* __restrict__ w1T,
                                           const float* __restrict__ b1,
                                           const unsigned short* __restrict__ w2T,
                                           const float* __restrict__ b2,
                                           unsigned short* __restrict__ z,
                                           float* __restrict__ y_sum)
{
    __shared__ __align__(16) unsigned short sx[64 * 96];
    __shared__ __align__(16) unsigned short su[64 * 648];
    int m0 = blockIdx.x * 64;
    int bidx = m0 >> 11;
    const float* xsrc = x + (size_t)m0 * CIN;
    for (int i = threadIdx.x; i < 64 * 96; i += 512) {
        int r = i / 96, c = i - r * 96;
        int slab = c >> 5, kc = c & 31;
        float v = 0.0f;
        if (slab == 0)      { if (kc < 14) v = xsrc[r * CIN + kc]; }
        else if (slab == 1) { if (kc < 22) v = xsrc[r * CIN + 14 + kc]; }
        else                { if (kc < 8)  v = xsrc[r * CIN + 36 + kc]; }
        sx[i] = f2bf(v);
    }
    __syncthreads();
    int wave = threadIdx.x >> 6, lane = threadIdx.x & 63, lid = lane & 15, quad = lane >> 4;
    const f32x4 z4 = {0.f, 0.f, 0.f, 0.f};
    // ---- stage 1: one K=32 MFMA per 16-col tile per 16-row band, silu -> su
    #pragma unroll
    for (int i = 0; i < 5; i++) {
        int ct = wave + 8 * i;
        int slab = ct >> 4;
        short8 bfr = *(const short8*)(w1T + (size_t)ct * 512 + lane * 8);
        int col = ct * 16 + lid;
        float bias = b1[col];
        #pragma unroll
        for (int rf = 0; rf < 4; rf++) {
            short8 a = *(const short8*)&sx[(rf * 16 + lid) * 96 + slab * 32 + quad * 8];
            f32x4 u = MFMA16(a, bfr, z4);
            #pragma unroll
            for (int r = 0; r < 4; r++) {
                float v0 = u[r] + bias;
                su[(rf * 16 + quad * 4 + r) * 648 + col] = f2bf(v0 / (1.0f + __expf(-v0)));
            }
        }
    }
    __syncthreads();
    // ---- stage 2
    int off[5];
    #pragma unroll
    for (int i = 0; i < 5; i++) {
        int ct = wave + 8 * i;
        off[i] = ((ct >> 2) * 32 + (ct & 3)) * 512 + lane * 8;
    }
    f32x4 acc[5][4];
    #pragma unroll
    for (int i = 0; i < 5; i++) { acc[i][0] = z4; acc[i][1] = z4; acc[i][2] = z4; acc[i][3] = z4; }
    short8 bA[5], bB[5];
    #pragma unroll
    for (int i = 0; i < 5; i++) bA[i] = *(const short8*)(w2T + off[i]);
    ZSTEP(0, bA, bB) ZSTEP(1, bB, bA) ZSTEP(2, bA, bB) ZSTEP(3, bB, bA)
    ZSTEP(4, bA, bB) ZSTEP(5, bB, bA) ZSTEP(6, bA, bB) ZSTEP(7, bB, bA)
    #pragma unroll
    for (int i = 0; i < 5; i++) {
        int ct = wave + 8 * i;
        int col = ct * 16 + lid;
        float bias = b2[col];
        float colsum = 0.0f;
        #pragma unroll
        for (int rf = 0; rf < 4; rf++) {
            #pragma unroll
            for (int r = 0; r < 4; r++) {
                float zv = acc[i][rf][r] + bias;
                z[(size_t)(m0 + rf * 16 + quad * 4 + r) * 640 + col] = f2bf(zv);
                colsum += zv;
            }
        }
        colsum += __shfl_xor(colsum, 16);
        colsum += __shfl_xor(colsum, 32);
        if (quad == 0) atomicAdd(&y_sum[bidx * 640 + col], colsum);
    }
}

// ---------------------------------------------------------------- SE MLP per batch
__global__ void k_se(const float* __restrict__ y_sum, const float* __restrict__ se_w1,
                     const float* __restrict__ se_w2, float* __restrict__ se)
{
    __shared__ float ya[640];
    __shared__ float rr[160];
    int b = blockIdx.x;
    for (int i = threadIdx.x; i < 640; i += 256) ya[i] = y_sum[b * 640 + i] * (1.0f / 2048.0f);
    __syncthreads();
    for (int o = threadIdx.x; o < 160; o += 256) {
        float a = 0.f;
        for (int k = 0; k < 640; k++) a += ya[k] * se_w1[k * 160 + o];
        rr[o] = fmaxf(a, 0.f);
    }
    __syncthreads();
    for (int c = threadIdx.x; c < 640; c += 256) {
        float a = 0.f;
        for (int o = 0; o < 160; o++) a += rr[o] * se_w2[o * 640 + c];
        se[b * 640 + c] = 1.0f / (1.0f + __expf(-a));
    }
}

// ---------------------------------------------------------------- GLU: g/p GEMMs + h + LN stats (8 waves, M=64)
// Each wave owns 64 rows x 5 tile-columns for BOTH g and p (acc 40 f32x4).
// Half-k-step rotation: issue P(kb) loads -> G-MFMAs(kb) -> issue G(kb+1) -> P-MFMAs(kb).
__global__ __launch_bounds__(512) void k_glu(const unsigned short* __restrict__ z,
                                             const float* __restrict__ se,
                                             const unsigned short* __restrict__ gwT,
                                             const unsigned short* __restrict__ pwT,
                                             const float* __restrict__ gb, const float* __restrict__ pb,
                                             unsigned short* __restrict__ h, float* __restrict__ hstats)
{
    __shared__ __align__(16) unsigned short sz[64 * 648];
    int m0 = blockIdx.x * 64;
    int bidx = m0 >> 11;
    const unsigned short* zsrc = z + (size_t)m0 * 640;
    const float* seb = se + bidx * 640;
    for (int i = threadIdx.x; i < 5120; i += 512) {        // stage z_se = bf16(z * se)
        int e = i * 8, r = e / 640, c = e - r * 640;
        short8 v = *(const short8*)(zsrc + e);
        unsigned short o8[8];
        #pragma unroll
        for (int j = 0; j < 8; j++) {
            float f = bf2f(((const unsigned short*)&v)[j]) * seb[c + j];
            o8[j] = f2bf(f);
        }
        *(short8*)&sz[r * 648 + c] = *(short8*)o8;
    }
    __syncthreads();
    int wave = threadIdx.x >> 6, lane = threadIdx.x & 63, lid = lane & 15, quad = lane >> 4;
    const f32x4 z4 = {0.f, 0.f, 0.f, 0.f};
    int off[5];
    #pragma unroll
    for (int i = 0; i < 5; i++) {
        int ct = wave + 8 * i;
        off[i] = ((ct >> 2) * 80 + (ct & 3)) * 512 + lane * 8;
    }
    f32x4 ag[5][4], ap[5][4];
    #pragma unroll
    for (int i = 0; i < 5; i++) {
        ag[i][0] = z4; ag[i][1] = z4; ag[i][2] = z4; ag[i][3] = z4;
        ap[i][0] = z4; ap[i][1] = z4; ap[i][2] = z4; ap[i][3] = z4;
    }
    short8 gbuf[5], pbuf[5];
    #pragma unroll
    for (int i = 0; i < 5; i++) gbuf[i] = *(const short8*)(gwT + off[i]);
    for (int kb = 0; kb < 20; kb++) {
        int kk = kb * 32;
        short8 a0 = *(const short8*)&sz[(0 * 16 + lid) * 648 + kk + quad * 8];
        short8 a1 = *(const short8*)&sz[(1 * 16 + lid) * 648 + kk + quad * 8];
        short8 a2 = *(const short8*)&sz[(2 * 16 + lid) * 648 + kk + quad * 8];
        short8 a3 = *(const short8*)&sz[(3 * 16 + lid) * 648 + kk + quad * 8];
        #pragma unroll
        for (int i = 0; i < 5; i++) pbuf[i] = *(const short8*)(pwT + off[i] + kk * 64);
        #pragma unroll
        for (int i = 0; i < 5; i++) {
            ag[i][0] = MFMA16(a0, gbuf[i], ag[i][0]);
            ag[i][1] = MFMA16(a1, gbuf[i], ag[i][1]);
            ag[i][2] = MFMA16(a2, gbuf[i], ag[i][2]);
            ag[i][3] = MFMA16(a3, gbuf[i], ag[i][3]);
        }
        if (kb < 19) {
            #pragma unroll
            for (int i = 0; i < 5; i++) gbuf[i] = *(const short8*)(gwT + off[i] + kk * 64 + 2048);
        }
        #pragma unroll
        for (int i = 0; i < 5; i++) {
            ap[i][0] = MFMA16(a0, pbuf[i], ap[i][0]);
            ap[i][1] = MFMA16(a1, pbuf[i], ap[i][1]);
            ap[i][2] = MFMA16(a2, pbuf[i], ap[i][2]);
            ap[i][3] = MFMA16(a3, pbuf[i], ap[i][3]);
        }
    }
    float hs[4][4] = {{0,0,0,0},{0,0,0,0},{0,0,0,0},{0,0,0,0}};
    float hq[4][4] = {{0,0,0,0},{0,0,0,0},{0,0,0,0},{0,0,0,0}};
    #pragma unroll
    for (int i = 0; i < 5; i++) {
        int ct = wave + 8 * i;
        int col = ct * 16 + lid;
        float gbv = gb[col], pbv = pb[col];
        #pragma unroll
        for (int rf = 0; rf < 4; rf++) {
            #pragma unroll
            for (int r = 0; r < 4; r++) {
                int row = rf * 16 + quad * 4 + r;
                float gl = ag[i][rf][r] + gbv;
                float pl = ap[i][rf][r] + pbv;
                float sg = 1.0f / (1.0f + __expf(-gl));
                float zv = bf2f(sz[row * 648 + col]);
                float hv = sg * pl + (1.0f - sg) * zv;
                h[(size_t)(m0 + row) * 640 + col] = f2bf(hv);
                hs[rf][r] += hv; hq[rf][r] += hv * hv;
            }
        }
    }
    #pragma unroll
    for (int s = 1; s < 16; s <<= 1) {
        #pragma unroll
        for (int rf = 0; rf < 4; rf++)
            #pragma unroll
            for (int r = 0; r < 4; r++) {
                hs[rf][r] += __shfl_xor(hs[rf][r], s);
                hq[rf][r] += __shfl_xor(hq[rf][r], s);
            }
    }
    if (lid == 0) {
        #pragma unroll
        for (int rf = 0; rf < 4; rf++)
            #pragma unroll
            for (int r = 0; r < 4; r++) {
                int row = m0 + rf * 16 + quad * 4 + r;
                atomicAdd(&hstats[row * 2 + 0], hs[rf][r]);
                atomicAdd(&hstats[row * 2 + 1], hq[rf][r]);
            }
    }
}

// ---------------------------------------------------------------- LN + out-proj GEMM + GN stats (8 waves, M=64)
// Each wave owns 64 rows x 4 tiles (ct = wave + 8i); full k-step dbuf.
#define OSTEP(KB, CUR, NXT) { \
    const int kk = (KB) * 32; \
    short8 a0 = *(const short8*)&sh[(0 * 16 + lid) * 648 + kk + quad * 8]; \
    short8 a1 = *(const short8*)&sh[(1 * 16 + lid) * 648 + kk + quad * 8]; \
    short8 a2 = *(const short8*)&sh[(2 * 16 + lid) * 648 + kk + quad * 8]; \
    short8 a3 = *(const short8*)&sh[(3 * 16 + lid) * 648 + kk + quad * 8]; \
    if ((KB) < 19) { \
        NXT[0] = *(const short8*)(owT + off[0] + ((KB) + 1) * 2048); \
        NXT[1] = *(const short8*)(owT + off[1] + ((KB) + 1) * 2048); \
        NXT[2] = *(const short8*)(owT + off[2] + ((KB) + 1) * 2048); \
        NXT[3] = *(const short8*)(owT + off[3] + ((KB) + 1) * 2048); \
    } \
    acc[0][0] = MFMA16(a0, CUR[0], acc[0][0]); acc[0][1] = MFMA16(a1, CUR[0], acc[0][1]); \
    acc[0][2] = MFMA16(a2, CUR[0], acc[0][2]); acc[0][3] = MFMA16(a3, CUR[0], acc[0][3]); \
    acc[1][0] = MFMA16(a0, CUR[1], acc[1][0]); acc[1][1] = MFMA16(a1, CUR[1], acc[1][1]); \
    acc[1][2] = MFMA16(a2, CUR[1], acc[1][2]); acc[1][3] = MFMA16(a3, CUR[1], acc[1][3]); \
    acc[2][0] = MFMA16(a0, CUR[2], acc[2][0]); acc[2][1] = MFMA16(a1, CUR[2], acc[2][1]); \
    acc[2][2] = MFMA16(a2, CUR[2], acc[2][2]); acc[2][3] = MFMA16(a3, CUR[2], acc[2][3]); \
    acc[3][0] = MFMA16(a0, CUR[3], acc[3][0]); acc[3][1] = MFMA16(a1, CUR[3], acc[3][1]); \
    acc[3][2] = MFMA16(a2, CUR[3], acc[3][2]); acc[3][3] = MFMA16(a3, CUR[3], acc[3][3]); }

__global__ __launch_bounds__(512) void k_out(const unsigned short* __restrict__ h,
                                             const float* __restrict__ hstats,
                                             const float* __restrict__ ln_w, const float* __restrict__ ln_b,
                                             const unsigned short* __restrict__ owT,
                                             const float* __restrict__ ob,
                                             float* __restrict__ outp, float* __restrict__ gnstats)
{
    __shared__ __align__(16) unsigned short sh[64 * 648];
    __shared__ float sA[64], sB[64];
    int m0 = blockIdx.x * 64;
    int bidx = m0 >> 11;
    if (threadIdx.x < 64) {
        float s1 = hstats[(m0 + threadIdx.x) * 2 + 0];
        float s2 = hstats[(m0 + threadIdx.x) * 2 + 1];
        float mu = s1 * (1.0f / 640.0f);
        float var = s2 * (1.0f / 640.0f) - mu * mu;
        float rs = rsqrtf(var + EPSV);
        sA[threadIdx.x] = rs;
        sB[threadIdx.x] = -mu * rs;
    }
    __syncthreads();
    const unsigned short* hsrc = h + (size_t)m0 * 640;
    for (int i = threadIdx.x; i < 5120; i += 512) {        // stage h_ln = bf16(LN(h))
        int e = i * 8, r = e / 640, c = e - r * 640;
        short8 v = *(const short8*)(hsrc + e);
        float a = sA[r], bb = sB[r];
        unsigned short o8[8];
        #pragma unroll
        for (int j = 0; j < 8; j++) {
            float f = bf2f(((const unsigned short*)&v)[j]);
            f = f * a + bb;
            f = f * ln_w[c + j] + ln_b[c + j];
            o8[j] = f2bf(f);
        }
        *(short8*)&sh[r * 648 + c] = *(short8*)o8;
    }
    __syncthreads();
    int wave = threadIdx.x >> 6, lane = threadIdx.x & 63, lid = lane & 15, quad = lane >> 4;
    const f32x4 z4 = {0.f, 0.f, 0.f, 0.f};
    int off[4];
    #pragma unroll
    for (int i = 0; i < 4; i++) {
        int ct = wave + 8 * i;
        off[i] = ((ct >> 2) * 80 + (ct & 3)) * 512 + lane * 8;
    }
    f32x4 acc[4][4];
    #pragma unroll
    for (int i = 0; i < 4; i++) {
        acc[i][0] = z4; acc[i][1] = z4; acc[i][2] = z4; acc[i][3] = z4;
    }
    short8 bA[4], bB[4];
    #pragma unroll
    for (int i = 0; i < 4; i++) bA[i] = *(const short8*)(owT + off[i]);
    OSTEP(0, bA, bB)  OSTEP(1, bB, bA)  OSTEP(2, bA, bB)  OSTEP(3, bB, bA)
    OSTEP(4, bA, bB)  OSTEP(5, bB, bA)  OSTEP(6, bA, bB)  OSTEP(7, bB, bA)
    OSTEP(8, bA, bB)  OSTEP(9, bB, bA)  OSTEP(10, bA, bB) OSTEP(11, bB, bA)
    OSTEP(12, bA, bB) OSTEP(13, bB, bA) OSTEP(14, bA, bB) OSTEP(15, bB, bA)
    OSTEP(16, bA, bB) OSTEP(17, bB, bA) OSTEP(18, bA, bB) OSTEP(19, bB, bA)
    #pragma unroll
    for (int i = 0; i < 4; i++) {
        int ct = wave + 8 * i;
        int col = ct * 16 + lid;
        float obv = ob[col];
        float gs = 0.f, gq = 0.f;
        #pragma unroll
        for (int rf = 0; rf < 4; rf++) {
            #pragma unroll
            for (int r = 0; r < 4; r++) {
                int row = rf * 16 + quad * 4 + r;
                float v = acc[i][rf][r] + obv;
                outp[(size_t)(m0 + row) * 512 + col] = v;
                gs += v; gq += v * v;
            }
        }
        #pragma unroll
        for (int s = 1; s < 64; s <<= 1) { gs += __shfl_xor(gs, s); gq += __shfl_xor(gq, s); }
        if (lane == 0) {
            int grp = ct >> 2;
            atomicAdd(&gnstats[(bidx * 8 + grp) * 2 + 0], gs);
            atomicAdd(&gnstats[(bidx * 8 + grp) * 2 + 1], gq);
        }
    }
}

// ---------------------------------------------------------------- GroupNorm finalize (in-place on d_out)
__global__ void k_gn(float* __restrict__ outp, const float* __restrict__ gnstats,
                     const float* __restrict__ gn_w, const float* __restrict__ gn_b)
{
    int idx = blockIdx.x * 256 + threadIdx.x;
    size_t e = (size_t)idx * 4;
    int c = (int)(e & 511);
    size_t row = e >> 9;
    int b = (int)(row >> 11);
    int grp = c >> 6;
    float s1 = gnstats[(b * 8 + grp) * 2 + 0];
    float s2 = gnstats[(b * 8 + grp) * 2 + 1];
    const float inv = 1.0f / 131072.0f;
    float mu = s1 * inv;
    float var = s2 * inv - mu * mu;
    float rs = rsqrtf(var + EPSV);
    float4 v = *(const float4*)(outp + e);
    float4 w = *(const float4*)(gn_w + c);
    float4 bb = *(const float4*)(gn_b + c);
    float4 o;
    o.x = (v.x - mu) * rs * w.x + bb.x;
    o.y = (v.y - mu) * rs * w.y + bb.y;
    o.z = (v.z - mu) * rs * w.z + bb.z;
    o.w = (v.w - mu) * rs * w.w + bb.w;
    *(float4*)(outp + e) = o;
}

// ----------------------------------------------------------------
extern "C" void kernel_launch(void* const* d_in, const int* in_sizes, int n_in,
                              void* d_out, int out_size, void* d_ws, size_t ws_size,
                              hipStream_t stream)
{
    const float* x     = (const float*)d_in[0];
    const float* hw1   = (const float*)d_in[1];
    const float* hb1   = (const float*)d_in[2];
    const float* hw2   = (const float*)d_in[3];
    const float* hb2   = (const float*)d_in[4];
    const float* lw1   = (const float*)d_in[5];
    const float* lb1   = (const float*)d_in[6];
    const float* lw2   = (const float*)d_in[7];
    const float* lb2   = (const float*)d_in[8];
    const float* ew1   = (const float*)d_in[9];
    const float* eb1   = (const float*)d_in[10];
    const float* ew2   = (const float*)d_in[11];
    const float* eb2   = (const float*)d_in[12];
    const float* se_w1 = (const float*)d_in[13];
    const float* se_w2 = (const float*)d_in[14];
    const float* gw    = (const float*)d_in[15];
    const float* gb    = (const float*)d_in[16];
    const float* pw    = (const float*)d_in[17];
    const float* pb    = (const float*)d_in[18];
    const float* ln_w  = (const float*)d_in[19];
    const float* ln_b  = (const float*)d_in[20];
    const float* ow    = (const float*)d_in[21];
    const float* ob    = (const float*)d_in[22];
    const float* gn_w  = (const float*)d_in[23];
    const float* gn_b  = (const float*)d_in[24];

    char* ws = (char*)d_ws;
    size_t off = 0;
    unsigned short* w2T  = (unsigned short*)(ws + off); off += (size_t)640 * 256 * 2;
    float*          b2   = (float*)(ws + off);          off += 640 * 4;
    unsigned short* gwT  = (unsigned short*)(ws + off); off += (size_t)640 * 640 * 2;
    unsigned short* pwT  = (unsigned short*)(ws + off); off += (size_t)640 * 640 * 2;
    unsigned short* owT  = (unsigned short*)(ws + off); off += (size_t)512 * 640 * 2;
    unsigned short* w1T  = (unsigned short*)(ws + off); off += (size_t)640 * 32 * 2;
    float*          b1   = (float*)(ws + off);          off += 640 * 4;
    float*          ysum = (float*)(ws + off);          off += (size_t)64 * 640 * 4;
    float*          sebuf= (float*)(ws + off);          off += (size_t)64 * 640 * 4;
    float*          hstat= (float*)(ws + off);          off += (size_t)BT * 2 * 4;
    float*          gnst = (float*)(ws + off);          off += (size_t)64 * 8 * 2 * 4;
    unsigned short* hbuf = (unsigned short*)(ws + off); off += (size_t)BT * 640 * 2;

    unsigned short* zbuf = (unsigned short*)d_out;
    float*          outp = (float*)d_out;

    hipMemsetAsync(ysum, 0, (size_t)64 * 640 * 4, stream);
    hipMemsetAsync(hstat, 0, (size_t)BT * 2 * 4, stream);
    hipMemsetAsync(gnst, 0, (size_t)64 * 8 * 2 * 4, stream);

    kprep<<<512, 256, 0, stream>>>(hw1, lw1, ew1, hb1, lb1, eb1,
                                   hw2, lw2, ew2, hb2, lb2, eb2,
                                   gw, pw, ow, w1T, b1, w2T, b2, gwT, pwT, owT);
    k_z<<<BT / 64, 512, 0, stream>>>(x, w1T, b1, w2T, b2, zbuf, ysum);
    k_se<<<64, 256, 0, stream>>>(ysum, se_w1, se_w2, sebuf);
    k_glu<<<BT / 64, 512, 0, stream>>>(zbuf, sebuf, gwT, pwT, gb, pb, hbuf, hstat);
    k_out<<<BT / 64, 512, 0, stream>>>(hbuf, hstat, ln_w, ln_b, owT, ob, outp, gnst);
    k_gn<<<(BT * 512) / (256 * 4), 256, 0, stream>>>(outp, gnst, gn_w, gn_b);
}